// Round 10
// baseline (172.808 us; speedup 1.0000x reference)
//
#include <hip/hip_runtime.h>

#define B_ 4
#define H_ 12
#define N_ 1028
#define D_ 64
#define R_ 4
#define L_ 3969
#define HID_ 32
#define KBLK 64
#define NT_ 17
#define NBH_ 48
#define QBLK 128
#define NQT 9              // ceil(1028/128)
#define NWG (NBH_*NQT)     // 432 = 8*54
#define TBL 3973           // per-h bias table stride: 4 zero-sentinels + 3969
#define LOG2E 1.4426950408889634f
#define SCL1 (0.125f*LOG2E)

typedef __attribute__((ext_vector_type(8)))  short bf16x8;
typedef __attribute__((ext_vector_type(4)))  float f32x4;
typedef __attribute__((ext_vector_type(4), aligned(4))) float f32x4u;  // 4B-aligned quad
typedef __attribute__((ext_vector_type(16))) float f32x16;
typedef __attribute__((ext_vector_type(2)))  unsigned int u32x2;
typedef __attribute__((ext_vector_type(4)))  unsigned int u32x4;
typedef __attribute__((address_space(3))) unsigned int lds_u32;
typedef const __attribute__((address_space(1))) unsigned int glb_u32;

__device__ __forceinline__ unsigned pkbf(float lo, float hi) {
  unsigned r;
  asm("v_cvt_pk_bf16_f32 %0, %1, %2" : "=v"(r) : "v"(lo), "v"(hi));
  return r;
}
__device__ __forceinline__ float exp2_fast(float x) {
  float r; asm("v_exp_f32 %0, %1" : "=v"(r) : "v"(x)); return r;
}
__device__ __forceinline__ float sgnlog1p(float x) {
  float t = log1pf(fabsf(x));
  return (x > 0.f) ? t : ((x < 0.f) ? -t : 0.f);
}

// ---- fused prep: bias tables (gscl folded ONCE) + K/V' images + raw mut ----
__global__ __launch_bounds__(256) void prep_kernel(
    const float* __restrict__ rel, const float* __restrict__ W1,
    const float* __restrict__ b1, const float* __restrict__ W2,
    const float* __restrict__ gammag, const float* __restrict__ kg,
    const float* __restrict__ vg, const float* __restrict__ mug,
    float* __restrict__ btgf, float* __restrict__ mut,
    unsigned short* __restrict__ kv)
{
  const int blk = blockIdx.x, tid = threadIdx.x;
  if (blk < 16) {
    // bias tables: btgf[h][4+l] = sigmoid(gamma_h)*log2e * bt[h][l]; [0..3]=0
    if (blk == 0 && tid < 48) btgf[(tid >> 2)*TBL + (tid & 3)] = 0.f;
    int l = blk*256 + tid;
    if (l < L_) {
      float r0 = rel[2*l], r1 = rel[2*l+1];
      float hid[HID_];
#pragma unroll
      for (int j = 0; j < HID_; ++j) {
        float x = W1[2*j]*r0 + W1[2*j+1]*r1 + b1[j];
        hid[j] = 0.5f * x * (1.f + erff(x * 0.70710678118654752f));
      }
#pragma unroll
      for (int h = 0; h < H_; ++h) {
        float acc = 0.f;
#pragma unroll
        for (int j = 0; j < HID_; ++j) acc += W2[h*HID_+j]*hid[j];
        float gscl = LOG2E / (1.f + __expf(-gammag[h]));
        btgf[h*TBL + 4 + l] = gscl * acc;
      }
    }
  } else if (blk < 16 + NBH_*NT_) {
    // K image [kc][d^swz] and V' image [d][swap23(kc)^swz] per (bh,t), bf16
    const int idx = blk - 16;
    const int bh = idx / NT_, t = idx - bh*NT_;
    const int k0 = t * KBLK;
    const float* kb = kg + (size_t)bh*N_*D_;
    const float* vb = vg + (size_t)bh*N_*D_;
    unsigned short* Ko = kv + (size_t)idx*8192;
    unsigned short* Vo = Ko + 4096;
    const int kcb = tid >> 4, d4 = (tid & 15)*4;
#pragma unroll
    for (int i = 0; i < 4; ++i) {
      int kc = kcb + i*16;
      int kr = k0 + kc; if (kr >= N_) kr = N_-1;
      f32x4 a = *(const f32x4*)(kb + (size_t)kr*D_ + d4);
      *(u32x2*)&Ko[kc*64 + (d4 ^ ((kc & 7) << 3))] = (u32x2){pkbf(a[0],a[1]), pkbf(a[2],a[3])};
    }
    const int vd0 = (tid >> 4)*4, vkc0 = (tid & 15)*4;
    const int vkc0p = ((vkc0 >> 1) & 4) | ((vkc0 << 1) & 8) | (vkc0 & 48); // kc bits2<->3
    f32x4 r[4];
#pragma unroll
    for (int i = 0; i < 4; ++i) {
      int kr = k0 + vkc0 + i; if (kr >= N_) kr = N_-1;
      r[i] = *(const f32x4*)(vb + (size_t)kr*D_ + vd0);
    }
#pragma unroll
    for (int j = 0; j < 4; ++j) {
      int d = vd0 + j;
      *(u32x2*)&Vo[d*64 + (vkc0p ^ ((d & 7) << 3))] =
          (u32x2){pkbf(r[0][j],r[1][j]), pkbf(r[2][j],r[3][j])};
    }
  } else {
    // mut = RAW sgnlog1p(mu_k), [bh][n], stride N_
    int idx = (blk - (16 + NBH_*NT_))*256 + tid;
    if (idx < NBH_*N_) {
      int bh = idx / N_, n = idx - bh*N_;
      int b = bh / H_, h = bh - b*H_;
      mut[idx] = sgnlog1p(mug[((size_t)b*2*H_ + H_ + h)*N_ + n]);
    }
  }
}

// ---- attn: 32x32x16 MFMA, 8 waves = 4 q-groups x 2 k-pipelines, in-block merge ----
// S^T = mfma(A=K,B=Q): D col=lane&31=q, row=(reg&3)+8(reg>>2)+4hi=kc(+32/blk). [m74/m101]
// P in regs (k-slot map == D kc pattern); V' image has kc bits2<->3 swapped.
// O^T = mfma(A=V',B=P) -> softmax state lane-local. Pipelines merge via LDS at end.
__global__ __launch_bounds__(512, 4) void attn_kernel(
    const float* __restrict__ qg, const float* __restrict__ mug,
    const float* __restrict__ btgf, const float* __restrict__ mut,
    const unsigned short* __restrict__ kv, float* __restrict__ outg)
{
  __shared__ __align__(16) unsigned short KV[2][2][8192]; // [pipe][dbuf]: K 8KB | V' 8KB

  const int tid = threadIdx.x;
  const int w = tid >> 6, lane = tid & 63, hi = lane >> 5, c = lane & 31;
  const int wp = w >> 2;          // k-pipeline (0: tiles 0..8, 1: tiles 9..16)
  const int wq = w & 3;           // q-group

  const int orig = blockIdx.x;
  const int wg = (orig & 7)*(NWG/8) + (orig >> 3);   // bijective: 432 % 8 == 0
  const int bh = wg / NQT;
  const int qt = wg - bh*NQT;
  const int b = bh / H_, h = bh - b*H_;
  const int q0 = qt * QBLK;

  const float* qb  = qg + (size_t)bh*N_*D_;
  const float* mt  = mut + (size_t)bh*N_;
  const float* bth = btgf + h*TBL;
  const unsigned short* kvb = kv + (size_t)bh*NT_*8192;

  // Q fragments (0.125*log2e folded)
  const int qrow = q0 + 32*wq + c;
  const int qrc = qrow < N_ ? qrow : N_-1;
  bf16x8 qf[4];
#pragma unroll
  for (int m = 0; m < 4; ++m) {
    const float* p = qb + (size_t)qrc*D_ + 16*m + 8*hi;
    f32x4 a0 = *(const f32x4*)p;
    f32x4 a1 = *(const f32x4*)(p + 4);
    u32x4 qw;
    qw[0] = pkbf(a0[0]*SCL1, a0[1]*SCL1); qw[1] = pkbf(a0[2]*SCL1, a0[3]*SCL1);
    qw[2] = pkbf(a1[0]*SCL1, a1[1]*SCL1); qw[3] = pkbf(a1[2]*SCL1, a1[3]*SCL1);
    qf[m] = __builtin_bit_cast(bf16x8, qw);
  }
  const float muq_c = (qrow < N_) ? sgnlog1p(mug[((size_t)b*2*H_ + h)*N_ + qrow]) : 0.f;
  const int qi = qrow - R_;
  const bool qok = (qi >= 0) && (qrow < N_);
  const int qy = qi >> 5, qx = qi & 31;
  const int lqc = qy*63 + qx + 1988;    // +4 sentinel +1984 geometry

  const int tbeg   = wp ? 9 : 0;
  const int tcount = wp ? 8 : 9;

  // staging: pipeline wp's 4 waves copy its 16KB tile (4KB per wave, 4x1KB glds)
  auto issue = [&](int tt, int pp) {
    const char* src = (const char*)(kvb + (size_t)tt*8192) + wq*4096;
    char* dst = (char*)&KV[wp][pp][0] + wq*4096;
#pragma unroll
    for (int j = 0; j < 4; ++j) {
      int o = j*1024;
      __builtin_amdgcn_global_load_lds((glb_u32*)(src + o + lane*16),
                                       (lds_u32*)(dst + o), 16, 0, 0);
    }
  };

  float mrun = -3.0e38f, lrun = 0.f;
  f32x16 Ot[2];
#pragma unroll
  for (int blk2 = 0; blk2 < 2; ++blk2)
#pragma unroll
    for (int r = 0; r < 16; ++r) Ot[blk2][r] = 0.f;

  issue(tbeg, 0);

  for (int i = 0; i < 9; ++i) {
    const bool act = i < tcount;
    const int t = tbeg + i;
    const int k0 = t * KBLK;
    const int p = i & 1;

    asm volatile("s_waitcnt vmcnt(0)" ::: "memory");   // this tile's glds landed
    __syncthreads();

    // ---- this-tile bias/mu loads (L1/L2-hot), issued BEFORE next glds so
    //      their wait leaves the glds in flight (vmcnt FIFO) ----
    f32x4 mkv[2][4], bvq[2][4];
    if (act) {
#pragma unroll
      for (int bb = 0; bb < 2; ++bb)
#pragma unroll
        for (int r2 = 0; r2 < 4; ++r2) {
          int kcb = 32*bb + 8*r2 + 4*hi;
          int mb = k0 + kcb; mb = mb > 1024 ? 1024 : mb;  // clamp: masked tail anyway
          mkv[bb][r2] = *(const f32x4*)&mt[mb];
          int ki0 = k0 + kcb - R_;
          int lk = (ki0 >> 5)*63 + (ki0 & 31);
          int va = lqc - lk;
          bool okq = ((unsigned)ki0 < 1024u) && qok;
          int basep = okq ? va : 3;                       // invalid -> zero sentinels
          bvq[bb][r2] = *(const f32x4u*)(bth + (basep - 3)); // bv[3-rr] = bias of rr
        }
    }
    __builtin_amdgcn_sched_barrier(0);
    if (i + 1 < tcount) issue(t + 1, p ^ 1);              // flies across compute

    if (act) {
      const unsigned short* Kl = &KV[wp][p][0];
      const unsigned short* Vl = &KV[wp][p][4096];

      // ---- S^T ----
      f32x16 sc[2];
#pragma unroll
      for (int bb = 0; bb < 2; ++bb)
#pragma unroll
        for (int r = 0; r < 16; ++r) sc[bb][r] = 0.f;
      __builtin_amdgcn_s_setprio(1);
#pragma unroll
      for (int m = 0; m < 4; ++m) {
        int sw = (c & 7) << 3;
        bf16x8 ka0 = *(const bf16x8*)&Kl[c*64      + ((16*m + 8*hi) ^ sw)];
        bf16x8 ka1 = *(const bf16x8*)&Kl[(32+c)*64 + ((16*m + 8*hi) ^ sw)];
        sc[0] = __builtin_amdgcn_mfma_f32_32x32x16_bf16(ka0, qf[m], sc[0], 0, 0, 0);
        sc[1] = __builtin_amdgcn_mfma_f32_32x32x16_bf16(ka1, qf[m], sc[1], 0, 0, 0);
      }
      __builtin_amdgcn_s_setprio(0);

      // ---- bias + tail mask + row max ----
      float smax = -3.0e38f;
#pragma unroll
      for (int bb = 0; bb < 2; ++bb)
#pragma unroll
        for (int r2 = 0; r2 < 4; ++r2) {
          const f32x4 mk = mkv[bb][r2], bv = bvq[bb][r2];
          int ki0 = k0 + 32*bb + 8*r2 + 4*hi - R_;
          bool mq = (ki0 < 1024);
#pragma unroll
          for (int rr = 0; rr < 4; ++rr) {
            float val = sc[bb][4*r2+rr] + (muq_c + mk[rr]) * bv[3-rr];
            val = mq ? val : -3.0e38f;
            sc[bb][4*r2+rr] = val;
            smax = fmaxf(smax, val);
          }
        }
      smax = fmaxf(smax, __shfl_xor(smax, 32));

      if (__any(smax > mrun)) {
        float mnew = fmaxf(mrun, smax);
        float corr = exp2_fast(mrun - mnew);
        lrun *= corr;
#pragma unroll
        for (int blk2 = 0; blk2 < 2; ++blk2)
#pragma unroll
          for (int r = 0; r < 16; ++r) Ot[blk2][r] *= corr;
        mrun = mnew;
      }

      float psum = 0.f;
#pragma unroll
      for (int bb = 0; bb < 2; ++bb)
#pragma unroll
        for (int r = 0; r < 16; ++r) {
          float pv = exp2_fast(sc[bb][r] - mrun);
          sc[bb][r] = pv;
          psum += pv;
        }
      psum += __shfl_xor(psum, 32);
      lrun += psum;

      u32x4 pa[4];
#pragma unroll
      for (int mm = 0; mm < 4; ++mm) {
        int bb = mm >> 1, s = (mm & 1) * 8;
#pragma unroll
        for (int j = 0; j < 4; ++j)
          pa[mm][j] = pkbf(sc[bb][s + 2*j], sc[bb][s + 2*j + 1]);
      }

      __builtin_amdgcn_s_setprio(1);
#pragma unroll
      for (int mm = 0; mm < 4; ++mm) {
        bf16x8 pfr = __builtin_bit_cast(bf16x8, pa[mm]);
        int sw = (c & 7) << 3;
        bf16x8 va0 = *(const bf16x8*)&Vl[c*64      + ((16*mm + 8*hi) ^ sw)];
        bf16x8 va1 = *(const bf16x8*)&Vl[(32+c)*64 + ((16*mm + 8*hi) ^ sw)];
        Ot[0] = __builtin_amdgcn_mfma_f32_32x32x16_bf16(va0, pfr, Ot[0], 0, 0, 0);
        Ot[1] = __builtin_amdgcn_mfma_f32_32x32x16_bf16(va1, pfr, Ot[1], 0, 0, 0);
      }
      __builtin_amdgcn_s_setprio(0);
    }
  }

  // ---- merge the two pipelines via LDS (lane layouts identical across pair) ----
  __syncthreads();                         // all tile LDS reads done; reuse KV
  float* sh = (float*)&KV[0][0][0];        // 4 pairs x 64 lanes x 34 f32 = 34.8KB
  const int base = (wq*64 + lane)*34;
  if (wp == 1) {
#pragma unroll
    for (int blk2 = 0; blk2 < 2; ++blk2)
#pragma unroll
      for (int r = 0; r < 16; ++r) sh[base + blk2*16 + r] = Ot[blk2][r];
    sh[base + 32] = mrun;
    sh[base + 33] = lrun;
  }
  __syncthreads();
  if (wp == 0) {
    float m1 = sh[base + 32], l1 = sh[base + 33];
    float M  = fmaxf(mrun, m1);
    float w0 = exp2_fast(mrun - M), w1 = exp2_fast(m1 - M);
    float rl = 1.f / (lrun*w0 + l1*w1);
    const int qo = q0 + 32*wq + c;
    if (qo < N_) {
      float* ob = outg + ((size_t)bh*N_ + qo)*64;
#pragma unroll
      for (int blk2 = 0; blk2 < 2; ++blk2)
#pragma unroll
        for (int r2 = 0; r2 < 4; ++r2) {
          f32x4 ov;
#pragma unroll
          for (int rr = 0; rr < 4; ++rr)
            ov[rr] = (Ot[blk2][4*r2+rr]*w0 + sh[base + blk2*16 + 4*r2 + rr]*w1) * rl;
          *(f32x4*)(ob + 8*r2 + 4*hi + 32*blk2) = ov;
        }
    }
  }
}

extern "C" void kernel_launch(void* const* d_in, const int* in_sizes, int n_in,
                              void* d_out, int out_size, void* d_ws, size_t ws_size,
                              hipStream_t stream) {
  const float* q     = (const float*)d_in[0];
  const float* k     = (const float*)d_in[1];
  const float* v     = (const float*)d_in[2];
  const float* mu    = (const float*)d_in[3];
  const float* rel   = (const float*)d_in[4];
  const float* W1    = (const float*)d_in[5];
  const float* b1    = (const float*)d_in[6];
  const float* W2    = (const float*)d_in[7];
  const float* gamma = (const float*)d_in[8];
  // d_in[9] idx_table unused: index computed analytically in-kernel.

  // ws layout (proven >= 13.76 MB available in round 6)
  char* wsb = (char*)d_ws;
  float* btgf = (float*)wsb;                               // 12*3973*4 = 190,704
  float* mut  = (float*)(wsb + 190704);                    // 48*1028*4 = 197,376
  unsigned short* kvimg = (unsigned short*)(wsb + 388080); // 48*17*8192*2 = 13,369,344

  const int prep_blocks = 16 + NBH_*NT_ + (NBH_*N_ + 255)/256;  // 16+816+193
  prep_kernel<<<dim3(prep_blocks), dim3(256), 0, stream>>>(rel, W1, b1, W2, gamma,
                                                           k, v, mu, btgf, mut, kvimg);
  attn_kernel<<<dim3(NWG), dim3(512), 0, stream>>>(q, mu, btgf, mut, kvimg,
                                                   (float*)d_out);
}

// Round 11
// 90.361 us; speedup vs baseline: 1.9124x; 1.9124x over previous
//
#include <hip/hip_runtime.h>

#define B_ 4
#define H_ 12
#define N_ 1028
#define D_ 64
#define R_ 4
#define L_ 3969
#define HID_ 32
#define KBLK 64
#define NT_ 17
#define NBH_ 48
#define QBLK 128
#define NQT 9              // ceil(1028/128)
#define NWG (NBH_*NQT)     // 432 = 8*54
#define TBL 3973           // per-h bias table stride: 4 zero-sentinels + 3969
#define LOG2E 1.4426950408889634f
#define SCL1 (0.125f*LOG2E)

typedef __attribute__((ext_vector_type(8)))  short bf16x8;
typedef __attribute__((ext_vector_type(4)))  float f32x4;
typedef __attribute__((ext_vector_type(16))) float f32x16;
typedef __attribute__((ext_vector_type(2)))  unsigned int u32x2;
typedef __attribute__((ext_vector_type(4)))  unsigned int u32x4;
typedef __attribute__((address_space(3))) unsigned int lds_u32;
typedef const __attribute__((address_space(1))) unsigned int glb_u32;

__device__ __forceinline__ unsigned pkbf(float lo, float hi) {
  unsigned r;
  asm("v_cvt_pk_bf16_f32 %0, %1, %2" : "=v"(r) : "v"(lo), "v"(hi));
  return r;
}
__device__ __forceinline__ float exp2_fast(float x) {
  float r; asm("v_exp_f32 %0, %1" : "=v"(r) : "v"(x)); return r;
}
__device__ __forceinline__ float sgnlog1p(float x) {
  float t = log1pf(fabsf(x));
  return (x > 0.f) ? t : ((x < 0.f) ? -t : 0.f);
}

// ---- fused prep: bias tables (gscl folded ONCE) + K/V' images + raw mut ----
__global__ __launch_bounds__(256) void prep_kernel(
    const float* __restrict__ rel, const float* __restrict__ W1,
    const float* __restrict__ b1, const float* __restrict__ W2,
    const float* __restrict__ gammag, const float* __restrict__ kg,
    const float* __restrict__ vg, const float* __restrict__ mug,
    float* __restrict__ btgf, float* __restrict__ mut,
    unsigned short* __restrict__ kv)
{
  const int blk = blockIdx.x, tid = threadIdx.x;
  if (blk < 16) {
    // bias tables: btgf[h][4+l] = sigmoid(gamma_h)*log2e * bt[h][l]; [0..3]=0
    if (blk == 0 && tid < 48) btgf[(tid >> 2)*TBL + (tid & 3)] = 0.f;
    int l = blk*256 + tid;
    if (l < L_) {
      float r0 = rel[2*l], r1 = rel[2*l+1];
      float hid[HID_];
#pragma unroll
      for (int j = 0; j < HID_; ++j) {
        float x = W1[2*j]*r0 + W1[2*j+1]*r1 + b1[j];
        hid[j] = 0.5f * x * (1.f + erff(x * 0.70710678118654752f));
      }
#pragma unroll
      for (int h = 0; h < H_; ++h) {
        float acc = 0.f;
#pragma unroll
        for (int j = 0; j < HID_; ++j) acc += W2[h*HID_+j]*hid[j];
        float gscl = LOG2E / (1.f + __expf(-gammag[h]));
        btgf[h*TBL + 4 + l] = gscl * acc;
      }
    }
  } else if (blk < 16 + NBH_*NT_) {
    // K image [kc][d^swz] and V' image [d][swap23(kc)^swz] per (bh,t), bf16
    const int idx = blk - 16;
    const int bh = idx / NT_, t = idx - bh*NT_;
    const int k0 = t * KBLK;
    const float* kb = kg + (size_t)bh*N_*D_;
    const float* vb = vg + (size_t)bh*N_*D_;
    unsigned short* Ko = kv + (size_t)idx*8192;
    unsigned short* Vo = Ko + 4096;
    const int kcb = tid >> 4, d4 = (tid & 15)*4;
#pragma unroll
    for (int i = 0; i < 4; ++i) {
      int kc = kcb + i*16;
      int kr = k0 + kc; if (kr >= N_) kr = N_-1;
      f32x4 a = *(const f32x4*)(kb + (size_t)kr*D_ + d4);
      *(u32x2*)&Ko[kc*64 + (d4 ^ ((kc & 7) << 3))] = (u32x2){pkbf(a[0],a[1]), pkbf(a[2],a[3])};
    }
    const int vd0 = (tid >> 4)*4, vkc0 = (tid & 15)*4;
    const int vkc0p = ((vkc0 >> 1) & 4) | ((vkc0 << 1) & 8) | (vkc0 & 48); // kc bits2<->3
    f32x4 r[4];
#pragma unroll
    for (int i = 0; i < 4; ++i) {
      int kr = k0 + vkc0 + i; if (kr >= N_) kr = N_-1;
      r[i] = *(const f32x4*)(vb + (size_t)kr*D_ + vd0);
    }
#pragma unroll
    for (int j = 0; j < 4; ++j) {
      int d = vd0 + j;
      *(u32x2*)&Vo[d*64 + (vkc0p ^ ((d & 7) << 3))] =
          (u32x2){pkbf(r[0][j],r[1][j]), pkbf(r[2][j],r[3][j])};
    }
  } else {
    // mut = RAW sgnlog1p(mu_k), [bh][n], stride N_
    int idx = (blk - (16 + NBH_*NT_))*256 + tid;
    if (idx < NBH_*N_) {
      int bh = idx / N_, n = idx - bh*N_;
      int b = bh / H_, h = bh - b*H_;
      mut[idx] = sgnlog1p(mug[((size_t)b*2*H_ + H_ + h)*N_ + n]);
    }
  }
}

// ---- attn: 32x32x16 MFMA, 8 waves = 4 q-groups x 2 k-pipelines, in-block merge ----
// S^T = mfma(A=K,B=Q): D col=lane&31=q, row=(reg&3)+8(reg>>2)+4hi=kc(+32/blk). [m74/m101]
// P in regs (k-slot map == D kc pattern); V' image has kc bits2<->3 swapped.
// O^T = mfma(A=V',B=P) -> softmax state lane-local. Pipelines merge via LDS at end.
// VGPR cap 128 via amdgpu_waves_per_eu(4) (NOT launch_bounds 2nd arg: empirically
// (512,4) -> 64-reg cap + 600MB spill traffic, r10).
__global__ __launch_bounds__(512) __attribute__((amdgpu_waves_per_eu(4)))
void attn_kernel(
    const float* __restrict__ qg, const float* __restrict__ mug,
    const float* __restrict__ btgf, const float* __restrict__ mut,
    const unsigned short* __restrict__ kv, float* __restrict__ outg)
{
  __shared__ __align__(16) unsigned short KV[2][2][8192]; // [pipe][dbuf]: K 8KB | V' 8KB
  __shared__ __align__(16) float btgs[TBL];               // 15.9KB; total 79.9KB -> 2 blk/CU

  const int tid = threadIdx.x;
  const int w = tid >> 6, lane = tid & 63, hi = lane >> 5, c = lane & 31;
  const int wp = w >> 2;          // k-pipeline (0: tiles 0..8, 1: tiles 9..16)
  const int wq = w & 3;           // q-group

  const int orig = blockIdx.x;
  const int wg = (orig & 7)*(NWG/8) + (orig >> 3);   // bijective: 432 % 8 == 0
  const int bh = wg / NQT;
  const int qt = wg - bh*NQT;
  const int b = bh / H_, h = bh - b*H_;
  const int q0 = qt * QBLK;

  const float* qb  = qg + (size_t)bh*N_*D_;
  const float* mt  = mut + (size_t)bh*N_;
  const unsigned short* kvb = kv + (size_t)bh*NT_*8192;

  // per-h bias table -> LDS (gscl already folded in prep)
  {
    const float* bth = btgf + h*TBL;
    for (int i = tid; i < TBL; i += 512) btgs[i] = bth[i];
  }

  // Q fragments (0.125*log2e folded)
  const int qrow = q0 + 32*wq + c;
  const int qrc = qrow < N_ ? qrow : N_-1;
  bf16x8 qf[4];
#pragma unroll
  for (int m = 0; m < 4; ++m) {
    const float* p = qb + (size_t)qrc*D_ + 16*m + 8*hi;
    f32x4 a0 = *(const f32x4*)p;
    f32x4 a1 = *(const f32x4*)(p + 4);
    u32x4 qw;
    qw[0] = pkbf(a0[0]*SCL1, a0[1]*SCL1); qw[1] = pkbf(a0[2]*SCL1, a0[3]*SCL1);
    qw[2] = pkbf(a1[0]*SCL1, a1[1]*SCL1); qw[3] = pkbf(a1[2]*SCL1, a1[3]*SCL1);
    qf[m] = __builtin_bit_cast(bf16x8, qw);
  }
  const float muq_c = (qrow < N_) ? sgnlog1p(mug[((size_t)b*2*H_ + h)*N_ + qrow]) : 0.f;
  const int qi = qrow - R_;
  const bool qok = (qi >= 0) && (qrow < N_);
  const int qy = qi >> 5, qx = qi & 31;
  const int lqc = qy*63 + qx + 1988;    // +4 sentinel +1984 geometry

  const int tbeg   = wp ? 9 : 0;
  const int tcount = wp ? 8 : 9;

  // staging: pipeline wp's 4 waves copy its 16KB tile (4KB per wave, 4x1KB glds)
  auto issue = [&](int tt, int pp) {
    const char* src = (const char*)(kvb + (size_t)tt*8192) + wq*4096;
    char* dst = (char*)&KV[wp][pp][0] + wq*4096;
#pragma unroll
    for (int j = 0; j < 4; ++j) {
      int o = j*1024;
      __builtin_amdgcn_global_load_lds((glb_u32*)(src + o + lane*16),
                                       (lds_u32*)(dst + o), 16, 0, 0);
    }
  };

  float mrun = -3.0e38f, lrun = 0.f;
  f32x16 Ot[2];
#pragma unroll
  for (int blk2 = 0; blk2 < 2; ++blk2)
#pragma unroll
    for (int r = 0; r < 16; ++r) Ot[blk2][r] = 0.f;

  issue(tbeg, 0);

  for (int i = 0; i < 9; ++i) {
    const bool act = i < tcount;
    const int t = tbeg + i;
    const int k0 = t * KBLK;
    const int p = i & 1;

    asm volatile("s_waitcnt vmcnt(0)" ::: "memory");   // this tile's glds landed
    __syncthreads();

    // ---- this-tile mu_k quads (L2-hot), issued BEFORE next glds so their
    //      wait leaves the glds in flight (vmcnt FIFO) ----
    f32x4 mkv[2][4];
    if (act) {
#pragma unroll
      for (int bb = 0; bb < 2; ++bb)
#pragma unroll
        for (int r2 = 0; r2 < 4; ++r2) {
          int mb = k0 + 32*bb + 8*r2 + 4*hi;
          mb = mb > 1024 ? 1024 : mb;                   // clamp: masked tail anyway
          mkv[bb][r2] = *(const f32x4*)&mt[mb];
        }
    }
    __builtin_amdgcn_sched_barrier(0);
    if (i + 1 < tcount) issue(t + 1, p ^ 1);            // flies across compute

    if (act) {
      const unsigned short* Kl = &KV[wp][p][0];
      const unsigned short* Vl = &KV[wp][p][4096];

      // ---- S^T ----
      f32x16 sc[2];
#pragma unroll
      for (int bb = 0; bb < 2; ++bb)
#pragma unroll
        for (int r = 0; r < 16; ++r) sc[bb][r] = 0.f;
      __builtin_amdgcn_s_setprio(1);
#pragma unroll
      for (int m = 0; m < 4; ++m) {
        int sw = (c & 7) << 3;
        bf16x8 ka0 = *(const bf16x8*)&Kl[c*64      + ((16*m + 8*hi) ^ sw)];
        bf16x8 ka1 = *(const bf16x8*)&Kl[(32+c)*64 + ((16*m + 8*hi) ^ sw)];
        sc[0] = __builtin_amdgcn_mfma_f32_32x32x16_bf16(ka0, qf[m], sc[0], 0, 0, 0);
        sc[1] = __builtin_amdgcn_mfma_f32_32x32x16_bf16(ka1, qf[m], sc[1], 0, 0, 0);
      }
      __builtin_amdgcn_s_setprio(0);

      // ---- bias (LDS gather, short live ranges) + tail mask + row max ----
      float smax = -3.0e38f;
#pragma unroll
      for (int bb = 0; bb < 2; ++bb)
#pragma unroll
        for (int r2 = 0; r2 < 4; ++r2) {
          const f32x4 mk = mkv[bb][r2];
          int ki0 = k0 + 32*bb + 8*r2 + 4*hi - R_;
          int lk = (ki0 >> 5)*63 + (ki0 & 31);
          int va = lqc - lk;
          bool okq = ((unsigned)ki0 < 1024u) && qok;
          int basep = okq ? va : 3;                     // invalid -> zero sentinels
          f32x4 bv;                                     // bv[3-rr] = bias of rr
          bv[0] = btgs[basep-3]; bv[1] = btgs[basep-2];
          bv[2] = btgs[basep-1]; bv[3] = btgs[basep];
          bool mq = (ki0 < 1024);
#pragma unroll
          for (int rr = 0; rr < 4; ++rr) {
            float val = sc[bb][4*r2+rr] + (muq_c + mk[rr]) * bv[3-rr];
            val = mq ? val : -3.0e38f;
            sc[bb][4*r2+rr] = val;
            smax = fmaxf(smax, val);
          }
        }
      smax = fmaxf(smax, __shfl_xor(smax, 32));

      if (__any(smax > mrun)) {
        float mnew = fmaxf(mrun, smax);
        float corr = exp2_fast(mrun - mnew);
        lrun *= corr;
#pragma unroll
        for (int blk2 = 0; blk2 < 2; ++blk2)
#pragma unroll
          for (int r = 0; r < 16; ++r) Ot[blk2][r] *= corr;
        mrun = mnew;
      }

      float psum = 0.f;
#pragma unroll
      for (int bb = 0; bb < 2; ++bb)
#pragma unroll
        for (int r = 0; r < 16; ++r) {
          float pv = exp2_fast(sc[bb][r] - mrun);
          sc[bb][r] = pv;
          psum += pv;
        }
      psum += __shfl_xor(psum, 32);
      lrun += psum;

      u32x4 pa[4];
#pragma unroll
      for (int mm = 0; mm < 4; ++mm) {
        int bb = mm >> 1, s = (mm & 1) * 8;
#pragma unroll
        for (int j = 0; j < 4; ++j)
          pa[mm][j] = pkbf(sc[bb][s + 2*j], sc[bb][s + 2*j + 1]);
      }

      __builtin_amdgcn_s_setprio(1);
#pragma unroll
      for (int mm = 0; mm < 4; ++mm) {
        bf16x8 pfr = __builtin_bit_cast(bf16x8, pa[mm]);
        int sw = (c & 7) << 3;
        bf16x8 va0 = *(const bf16x8*)&Vl[c*64      + ((16*mm + 8*hi) ^ sw)];
        bf16x8 va1 = *(const bf16x8*)&Vl[(32+c)*64 + ((16*mm + 8*hi) ^ sw)];
        Ot[0] = __builtin_amdgcn_mfma_f32_32x32x16_bf16(va0, pfr, Ot[0], 0, 0, 0);
        Ot[1] = __builtin_amdgcn_mfma_f32_32x32x16_bf16(va1, pfr, Ot[1], 0, 0, 0);
      }
      __builtin_amdgcn_s_setprio(0);
    }
  }

  // ---- merge the two pipelines via LDS (lane layouts identical across pair) ----
  __syncthreads();                         // all tile LDS reads done; reuse KV
  float* sh = (float*)&KV[0][0][0];        // 4 pairs x 64 lanes x 34 f32 = 34.8KB
  const int base = (wq*64 + lane)*34;
  if (wp == 1) {
#pragma unroll
    for (int blk2 = 0; blk2 < 2; ++blk2)
#pragma unroll
      for (int r = 0; r < 16; ++r) sh[base + blk2*16 + r] = Ot[blk2][r];
    sh[base + 32] = mrun;
    sh[base + 33] = lrun;
  }
  __syncthreads();
  if (wp == 0) {
    float m1 = sh[base + 32], l1 = sh[base + 33];
    float M  = fmaxf(mrun, m1);
    float w0 = exp2_fast(mrun - M), w1 = exp2_fast(m1 - M);
    float rl = 1.f / (lrun*w0 + l1*w1);
    const int qo = q0 + 32*wq + c;
    if (qo < N_) {
      float* ob = outg + ((size_t)bh*N_ + qo)*64;
#pragma unroll
      for (int blk2 = 0; blk2 < 2; ++blk2)
#pragma unroll
        for (int r2 = 0; r2 < 4; ++r2) {
          f32x4 ov;
#pragma unroll
          for (int rr = 0; rr < 4; ++rr)
            ov[rr] = (Ot[blk2][4*r2+rr]*w0 + sh[base + blk2*16 + 4*r2 + rr]*w1) * rl;
          *(f32x4*)(ob + 8*r2 + 4*hi + 32*blk2) = ov;
        }
    }
  }
}

extern "C" void kernel_launch(void* const* d_in, const int* in_sizes, int n_in,
                              void* d_out, int out_size, void* d_ws, size_t ws_size,
                              hipStream_t stream) {
  const float* q     = (const float*)d_in[0];
  const float* k     = (const float*)d_in[1];
  const float* v     = (const float*)d_in[2];
  const float* mu    = (const float*)d_in[3];
  const float* rel   = (const float*)d_in[4];
  const float* W1    = (const float*)d_in[5];
  const float* b1    = (const float*)d_in[6];
  const float* W2    = (const float*)d_in[7];
  const float* gamma = (const float*)d_in[8];
  // d_in[9] idx_table unused: index computed analytically in-kernel.

  // ws layout (proven >= 13.76 MB available in round 6)
  char* wsb = (char*)d_ws;
  float* btgf = (float*)wsb;                               // 12*3973*4 = 190,704
  float* mut  = (float*)(wsb + 190704);                    // 48*1028*4 = 197,376
  unsigned short* kvimg = (unsigned short*)(wsb + 388080); // 48*17*8192*2 = 13,369,344

  const int prep_blocks = 16 + NBH_*NT_ + (NBH_*N_ + 255)/256;  // 16+816+193
  prep_kernel<<<dim3(prep_blocks), dim3(256), 0, stream>>>(rel, W1, b1, W2, gamma,
                                                           k, v, mu, btgf, mut, kvimg);
  attn_kernel<<<dim3(NWG), dim3(512), 0, stream>>>(q, mu, btgf, mut, kvimg,
                                                   (float*)d_out);
}

// Round 12
// 69.538 us; speedup vs baseline: 2.4851x; 1.2994x over previous
//
#include <hip/hip_runtime.h>

#define B_ 4
#define H_ 12
#define N_ 1028
#define D_ 64
#define R_ 4
#define L_ 3969
#define HID_ 32
#define KBLK 64
#define NT_ 17
#define NBH_ 48
#define QBLK 128
#define NQT 9              // ceil(1028/128)
#define NWG (NBH_*NQT)     // 432 = 8*54
#define TBL 3973           // per-h bias table stride: 4 zero-sentinels + 3969
#define LOG2E 1.4426950408889634f
#define SCL1 (0.125f*LOG2E)

typedef __attribute__((ext_vector_type(8)))  short bf16x8;
typedef __attribute__((ext_vector_type(4)))  float f32x4;
typedef __attribute__((ext_vector_type(16))) float f32x16;
typedef __attribute__((ext_vector_type(2)))  unsigned int u32x2;
typedef __attribute__((ext_vector_type(4)))  unsigned int u32x4;
typedef __attribute__((address_space(3))) unsigned int lds_u32;
typedef const __attribute__((address_space(1))) unsigned int glb_u32;

__device__ __forceinline__ unsigned pkbf(float lo, float hi) {
  unsigned r;
  asm("v_cvt_pk_bf16_f32 %0, %1, %2" : "=v"(r) : "v"(lo), "v"(hi));
  return r;
}
__device__ __forceinline__ float exp2_fast(float x) {
  float r; asm("v_exp_f32 %0, %1" : "=v"(r) : "v"(x)); return r;
}
__device__ __forceinline__ float sgnlog1p(float x) {
  float t = log1pf(fabsf(x));
  return (x > 0.f) ? t : ((x < 0.f) ? -t : 0.f);
}

// ---- fused prep: bias tables (gscl folded ONCE) + K/V' images + raw mut ----
__global__ __launch_bounds__(256) void prep_kernel(
    const float* __restrict__ rel, const float* __restrict__ W1,
    const float* __restrict__ b1, const float* __restrict__ W2,
    const float* __restrict__ gammag, const float* __restrict__ kg,
    const float* __restrict__ vg, const float* __restrict__ mug,
    float* __restrict__ btgf, float* __restrict__ mut,
    unsigned short* __restrict__ kv)
{
  const int blk = blockIdx.x, tid = threadIdx.x;
  if (blk < 16) {
    // bias tables: btgf[h][4+l] = sigmoid(gamma_h)*log2e * bt[h][l]; [0..3]=0
    if (blk == 0 && tid < 48) btgf[(tid >> 2)*TBL + (tid & 3)] = 0.f;
    int l = blk*256 + tid;
    if (l < L_) {
      float r0 = rel[2*l], r1 = rel[2*l+1];
      float hid[HID_];
#pragma unroll
      for (int j = 0; j < HID_; ++j) {
        float x = W1[2*j]*r0 + W1[2*j+1]*r1 + b1[j];
        hid[j] = 0.5f * x * (1.f + erff(x * 0.70710678118654752f));
      }
#pragma unroll
      for (int h = 0; h < H_; ++h) {
        float acc = 0.f;
#pragma unroll
        for (int j = 0; j < HID_; ++j) acc += W2[h*HID_+j]*hid[j];
        float gscl = LOG2E / (1.f + __expf(-gammag[h]));
        btgf[h*TBL + 4 + l] = gscl * acc;
      }
    }
  } else if (blk < 16 + NBH_*NT_) {
    // K image [kc][d^swz] and V' image [d][swap23(kc)^swz] per (bh,t), bf16
    const int idx = blk - 16;
    const int bh = idx / NT_, t = idx - bh*NT_;
    const int k0 = t * KBLK;
    const float* kb = kg + (size_t)bh*N_*D_;
    const float* vb = vg + (size_t)bh*N_*D_;
    unsigned short* Ko = kv + (size_t)idx*8192;
    unsigned short* Vo = Ko + 4096;
    const int kcb = tid >> 4, d4 = (tid & 15)*4;
#pragma unroll
    for (int i = 0; i < 4; ++i) {
      int kc = kcb + i*16;
      int kr = k0 + kc; if (kr >= N_) kr = N_-1;
      f32x4 a = *(const f32x4*)(kb + (size_t)kr*D_ + d4);
      *(u32x2*)&Ko[kc*64 + (d4 ^ ((kc & 7) << 3))] = (u32x2){pkbf(a[0],a[1]), pkbf(a[2],a[3])};
    }
    const int vd0 = (tid >> 4)*4, vkc0 = (tid & 15)*4;
    const int vkc0p = ((vkc0 >> 1) & 4) | ((vkc0 << 1) & 8) | (vkc0 & 48); // kc bits2<->3
    f32x4 r[4];
#pragma unroll
    for (int i = 0; i < 4; ++i) {
      int kr = k0 + vkc0 + i; if (kr >= N_) kr = N_-1;
      r[i] = *(const f32x4*)(vb + (size_t)kr*D_ + vd0);
    }
#pragma unroll
    for (int j = 0; j < 4; ++j) {
      int d = vd0 + j;
      *(u32x2*)&Vo[d*64 + (vkc0p ^ ((d & 7) << 3))] =
          (u32x2){pkbf(r[0][j],r[1][j]), pkbf(r[2][j],r[3][j])};
    }
  } else {
    // mut = RAW sgnlog1p(mu_k), [bh][n], stride N_
    int idx = (blk - (16 + NBH_*NT_))*256 + tid;
    if (idx < NBH_*N_) {
      int bh = idx / N_, n = idx - bh*N_;
      int b = bh / H_, h = bh - b*H_;
      mut[idx] = sgnlog1p(mug[((size_t)b*2*H_ + H_ + h)*N_ + n]);
    }
  }
}

// ---- attn: 32x32x16 MFMA, 8 waves = 4 q-groups x 2 k-pipelines, in-block merge ----
// S^T = mfma(A=K,B=Q): D col=lane&31=q, row=(reg&3)+8(reg>>2)+4hi=kc(+32/blk). [m74/m101]
// P in regs (k-slot map == D kc pattern); V' image has kc bits2<->3 swapped.
// O^T = mfma(A=V',B=P) -> softmax state lane-local. Pipelines merge via LDS at end.
// REGISTER BUDGET: (512,2) is the ONLY proven no-spill config for this datapath
// (r7: 92 VGPR, WRITE=output-only). (512,4) -> 64-reg cap + 364MB spill (r10);
// (512)+waves_per_eu(4) -> still 64 + 85MB spill (r11). Do not change.
__global__ __launch_bounds__(512, 2) void attn_kernel(
    const float* __restrict__ qg, const float* __restrict__ mug,
    const float* __restrict__ btgf, const float* __restrict__ mut,
    const unsigned short* __restrict__ kv, float* __restrict__ outg)
{
  __shared__ __align__(16) unsigned short KV[2][2][8192]; // [pipe][dbuf]: K 8KB | V' 8KB
  __shared__ __align__(16) float btgs[TBL];               // 15.9KB; total 79.9KB -> 2 blk/CU

  const int tid = threadIdx.x;
  const int w = tid >> 6, lane = tid & 63, hi = lane >> 5, c = lane & 31;
  const int wp = w >> 2;          // k-pipeline (0: tiles 0..8, 1: tiles 9..16)
  const int wq = w & 3;           // q-group

  const int orig = blockIdx.x;
  const int wg = (orig & 7)*(NWG/8) + (orig >> 3);   // bijective: 432 % 8 == 0
  const int bh = wg / NQT;
  const int qt = wg - bh*NQT;
  const int b = bh / H_, h = bh - b*H_;
  const int q0 = qt * QBLK;

  const float* qb  = qg + (size_t)bh*N_*D_;
  const float* mt  = mut + (size_t)bh*N_;
  const unsigned short* kvb = kv + (size_t)bh*NT_*8192;

  // per-h bias table -> LDS (gscl already folded in prep)
  {
    const float* bth = btgf + h*TBL;
    for (int i = tid; i < TBL; i += 512) btgs[i] = bth[i];
  }

  // Q fragments (0.125*log2e folded)
  const int qrow = q0 + 32*wq + c;
  const int qrc = qrow < N_ ? qrow : N_-1;
  bf16x8 qf[4];
#pragma unroll
  for (int m = 0; m < 4; ++m) {
    const float* p = qb + (size_t)qrc*D_ + 16*m + 8*hi;
    f32x4 a0 = *(const f32x4*)p;
    f32x4 a1 = *(const f32x4*)(p + 4);
    u32x4 qw;
    qw[0] = pkbf(a0[0]*SCL1, a0[1]*SCL1); qw[1] = pkbf(a0[2]*SCL1, a0[3]*SCL1);
    qw[2] = pkbf(a1[0]*SCL1, a1[1]*SCL1); qw[3] = pkbf(a1[2]*SCL1, a1[3]*SCL1);
    qf[m] = __builtin_bit_cast(bf16x8, qw);
  }
  const float muq_c = (qrow < N_) ? sgnlog1p(mug[((size_t)b*2*H_ + h)*N_ + qrow]) : 0.f;
  const int qi = qrow - R_;
  const bool qok = (qi >= 0) && (qrow < N_);
  const int qy = qi >> 5, qx = qi & 31;
  const int lqc = qy*63 + qx + 1988;    // +4 sentinel +1984 geometry

  const int tbeg   = wp ? 9 : 0;
  const int tcount = wp ? 8 : 9;

  // staging: pipeline wp's 4 waves copy its 16KB tile (4KB per wave, 4x1KB glds)
  auto issue = [&](int tt, int pp) {
    const char* src = (const char*)(kvb + (size_t)tt*8192) + wq*4096;
    char* dst = (char*)&KV[wp][pp][0] + wq*4096;
#pragma unroll
    for (int j = 0; j < 4; ++j) {
      int o = j*1024;
      __builtin_amdgcn_global_load_lds((glb_u32*)(src + o + lane*16),
                                       (lds_u32*)(dst + o), 16, 0, 0);
    }
  };

  float mrun = -3.0e38f, lrun = 0.f;
  f32x16 Ot[2];
#pragma unroll
  for (int blk2 = 0; blk2 < 2; ++blk2)
#pragma unroll
    for (int r = 0; r < 16; ++r) Ot[blk2][r] = 0.f;

  issue(tbeg, 0);

  for (int i = 0; i < 9; ++i) {
    const bool act = i < tcount;
    const int t = tbeg + i;
    const int k0 = t * KBLK;
    const int p = i & 1;

    asm volatile("s_waitcnt vmcnt(0)" ::: "memory");   // this tile's glds landed
    __syncthreads();

    // ---- this-tile mu_k quads (L2-hot), issued BEFORE next glds so their
    //      wait leaves the glds in flight (vmcnt FIFO) ----
    f32x4 mkv[2][4];
    if (act) {
#pragma unroll
      for (int bb = 0; bb < 2; ++bb)
#pragma unroll
        for (int r2 = 0; r2 < 4; ++r2) {
          int mb = k0 + 32*bb + 8*r2 + 4*hi;
          mb = mb > 1024 ? 1024 : mb;                   // clamp: masked tail anyway
          mkv[bb][r2] = *(const f32x4*)&mt[mb];
        }
    }
    __builtin_amdgcn_sched_barrier(0);
    if (i + 1 < tcount) issue(t + 1, p ^ 1);            // flies across compute

    if (act) {
      const unsigned short* Kl = &KV[wp][p][0];
      const unsigned short* Vl = &KV[wp][p][4096];

      // ---- S^T ----
      f32x16 sc[2];
#pragma unroll
      for (int bb = 0; bb < 2; ++bb)
#pragma unroll
        for (int r = 0; r < 16; ++r) sc[bb][r] = 0.f;
      __builtin_amdgcn_s_setprio(1);
#pragma unroll
      for (int m = 0; m < 4; ++m) {
        int sw = (c & 7) << 3;
        bf16x8 ka0 = *(const bf16x8*)&Kl[c*64      + ((16*m + 8*hi) ^ sw)];
        bf16x8 ka1 = *(const bf16x8*)&Kl[(32+c)*64 + ((16*m + 8*hi) ^ sw)];
        sc[0] = __builtin_amdgcn_mfma_f32_32x32x16_bf16(ka0, qf[m], sc[0], 0, 0, 0);
        sc[1] = __builtin_amdgcn_mfma_f32_32x32x16_bf16(ka1, qf[m], sc[1], 0, 0, 0);
      }
      __builtin_amdgcn_s_setprio(0);

      // ---- bias (LDS gather, short live ranges) + tail mask + row max ----
      float smax = -3.0e38f;
#pragma unroll
      for (int bb = 0; bb < 2; ++bb)
#pragma unroll
        for (int r2 = 0; r2 < 4; ++r2) {
          const f32x4 mk = mkv[bb][r2];
          int ki0 = k0 + 32*bb + 8*r2 + 4*hi - R_;
          int lk = (ki0 >> 5)*63 + (ki0 & 31);
          int va = lqc - lk;
          bool okq = ((unsigned)ki0 < 1024u) && qok;
          int basep = okq ? va : 3;                     // invalid -> zero sentinels
          f32x4 bv;                                     // bv[3-rr] = bias of rr
          bv[0] = btgs[basep-3]; bv[1] = btgs[basep-2];
          bv[2] = btgs[basep-1]; bv[3] = btgs[basep];
          bool mq = (ki0 < 1024);
#pragma unroll
          for (int rr = 0; rr < 4; ++rr) {
            float val = sc[bb][4*r2+rr] + (muq_c + mk[rr]) * bv[3-rr];
            val = mq ? val : -3.0e38f;
            sc[bb][4*r2+rr] = val;
            smax = fmaxf(smax, val);
          }
        }
      smax = fmaxf(smax, __shfl_xor(smax, 32));

      if (__any(smax > mrun)) {
        float mnew = fmaxf(mrun, smax);
        float corr = exp2_fast(mrun - mnew);
        lrun *= corr;
#pragma unroll
        for (int blk2 = 0; blk2 < 2; ++blk2)
#pragma unroll
          for (int r = 0; r < 16; ++r) Ot[blk2][r] *= corr;
        mrun = mnew;
      }

      float psum = 0.f;
#pragma unroll
      for (int bb = 0; bb < 2; ++bb)
#pragma unroll
        for (int r = 0; r < 16; ++r) {
          float pv = exp2_fast(sc[bb][r] - mrun);
          sc[bb][r] = pv;
          psum += pv;
        }
      psum += __shfl_xor(psum, 32);
      lrun += psum;

      u32x4 pa[4];
#pragma unroll
      for (int mm = 0; mm < 4; ++mm) {
        int bb = mm >> 1, s = (mm & 1) * 8;
#pragma unroll
        for (int j = 0; j < 4; ++j)
          pa[mm][j] = pkbf(sc[bb][s + 2*j], sc[bb][s + 2*j + 1]);
      }

      __builtin_amdgcn_s_setprio(1);
#pragma unroll
      for (int mm = 0; mm < 4; ++mm) {
        bf16x8 pfr = __builtin_bit_cast(bf16x8, pa[mm]);
        int sw = (c & 7) << 3;
        bf16x8 va0 = *(const bf16x8*)&Vl[c*64      + ((16*mm + 8*hi) ^ sw)];
        bf16x8 va1 = *(const bf16x8*)&Vl[(32+c)*64 + ((16*mm + 8*hi) ^ sw)];
        Ot[0] = __builtin_amdgcn_mfma_f32_32x32x16_bf16(va0, pfr, Ot[0], 0, 0, 0);
        Ot[1] = __builtin_amdgcn_mfma_f32_32x32x16_bf16(va1, pfr, Ot[1], 0, 0, 0);
      }
      __builtin_amdgcn_s_setprio(0);
    }
  }

  // ---- merge the two pipelines via LDS (lane layouts identical across pair) ----
  __syncthreads();                         // all tile LDS reads done; reuse KV
  float* sh = (float*)&KV[0][0][0];        // 4 pairs x 64 lanes x 34 f32 = 34.8KB
  const int base = (wq*64 + lane)*34;
  if (wp == 1) {
#pragma unroll
    for (int blk2 = 0; blk2 < 2; ++blk2)
#pragma unroll
      for (int r = 0; r < 16; ++r) sh[base + blk2*16 + r] = Ot[blk2][r];
    sh[base + 32] = mrun;
    sh[base + 33] = lrun;
  }
  __syncthreads();
  if (wp == 0) {
    float m1 = sh[base + 32], l1 = sh[base + 33];
    float M  = fmaxf(mrun, m1);
    float w0 = exp2_fast(mrun - M), w1 = exp2_fast(m1 - M);
    float rl = 1.f / (lrun*w0 + l1*w1);
    const int qo = q0 + 32*wq + c;
    if (qo < N_) {
      float* ob = outg + ((size_t)bh*N_ + qo)*64;
#pragma unroll
      for (int blk2 = 0; blk2 < 2; ++blk2)
#pragma unroll
        for (int r2 = 0; r2 < 4; ++r2) {
          f32x4 ov;
#pragma unroll
          for (int rr = 0; rr < 4; ++rr)
            ov[rr] = (Ot[blk2][4*r2+rr]*w0 + sh[base + blk2*16 + 4*r2 + rr]*w1) * rl;
          *(f32x4*)(ob + 8*r2 + 4*hi + 32*blk2) = ov;
        }
    }
  }
}

extern "C" void kernel_launch(void* const* d_in, const int* in_sizes, int n_in,
                              void* d_out, int out_size, void* d_ws, size_t ws_size,
                              hipStream_t stream) {
  const float* q     = (const float*)d_in[0];
  const float* k     = (const float*)d_in[1];
  const float* v     = (const float*)d_in[2];
  const float* mu    = (const float*)d_in[3];
  const float* rel   = (const float*)d_in[4];
  const float* W1    = (const float*)d_in[5];
  const float* b1    = (const float*)d_in[6];
  const float* W2    = (const float*)d_in[7];
  const float* gamma = (const float*)d_in[8];
  // d_in[9] idx_table unused: index computed analytically in-kernel.

  // ws layout (proven >= 13.76 MB available in round 6)
  char* wsb = (char*)d_ws;
  float* btgf = (float*)wsb;                               // 12*3973*4 = 190,704
  float* mut  = (float*)(wsb + 190704);                    // 48*1028*4 = 197,376
  unsigned short* kvimg = (unsigned short*)(wsb + 388080); // 48*17*8192*2 = 13,369,344

  const int prep_blocks = 16 + NBH_*NT_ + (NBH_*N_ + 255)/256;  // 16+816+193
  prep_kernel<<<dim3(prep_blocks), dim3(256), 0, stream>>>(rel, W1, b1, W2, gamma,
                                                           k, v, mu, btgf, mut, kvimg);
  attn_kernel<<<dim3(NWG), dim3(512), 0, stream>>>(q, mu, btgf, mut, kvimg,
                                                   (float*)d_out);
}